// Round 10
// baseline (53.412 us; speedup 1.0000x reference)
//
#include <hip/hip_runtime.h>

#define NEG_SLOPE 0.2f

typedef __bf16 bf16x8 __attribute__((ext_vector_type(8)));
typedef float  f32x4  __attribute__((ext_vector_type(4)));
typedef float  f32x2  __attribute__((ext_vector_type(2)));

__device__ __forceinline__ float relu_f(float v) { return v > 0.f ? v : 0.f; }
__device__ __forceinline__ f32x2 pk_fma(f32x2 a, f32x2 b, f32x2 c) { return __builtin_elementwise_fma(a, b, c); }
__device__ __forceinline__ f32x2 pk_max(f32x2 a, f32x2 b) { return __builtin_elementwise_max(a, b); }
__device__ __forceinline__ f32x2 splat2(float s) { f32x2 r = {s, s}; return r; }
__device__ __forceinline__ f32x2 ld2(const float* p) { return *reinterpret_cast<const f32x2*>(p); }

// ---------------- prep: W1/W2 -> bf16 MFMA B-fragment order (validated R7-R9) ----------------
__global__ __launch_bounds__(256)
void prep_weights(const float* __restrict__ W1, const float* __restrict__ W2,
                  __bf16* __restrict__ W1F, __bf16* __restrict__ W2F)
{
    int idx = blockIdx.x * 256 + threadIdx.x;   // 0..8191
    int half = idx >> 12;                        // 0: W1, 1: W2
    int e    = idx & 4095;
    int j   = e & 7;
    int l   = (e >> 3) & 63;
    int t   = e >> 9;                            // 0..7
    int l15 = l & 15;
    int l4  = l >> 4;
    if (half == 0) {
        W1F[e] = (__bf16)W1[(l4 * 8 + j) * 128 + t * 16 + l15];
    } else {
        int ks = t >> 1, nn = t & 1;
        W2F[e] = (__bf16)W2[(j * 16 + ks * 4 + l4) * 32 + nn * 16 + l15];
    }
}

// build the 14-feature vector for node j of sample b (g uniform per wave)
__device__ __forceinline__ void build_xf(
    int g, int j, int b, const float px[3], const float py[3],
    const float* __restrict__ agent_vel, const float* __restrict__ rel_lm,
    const float* __restrict__ other_pos, float xf[14])
{
    const int o0[3] = {1, 0, 0};
    const int o1[3] = {2, 2, 1};
    if (g == 0) {
        const float2 vel = reinterpret_cast<const float2*>(agent_vel + b * 6)[j];
        const float2* rl = reinterpret_cast<const float2*>(rel_lm + b * 18 + j * 6);
        const float4 op  = reinterpret_cast<const float4*>(other_pos + b * 12)[j];
        xf[0] = px[j]; xf[1] = py[j];
        xf[2] = vel.x; xf[3] = vel.y;
        xf[4] = rl[0].x; xf[5] = rl[0].y;
        xf[6] = rl[1].x; xf[7] = rl[1].y;
        xf[8] = rl[2].x; xf[9] = rl[2].y;
        xf[10] = op.x; xf[11] = op.y; xf[12] = op.z; xf[13] = op.w;
    } else {
        xf[0] = px[j]; xf[1] = py[j];
        xf[2] = 0.f;   xf[3] = 0.f;
#pragma unroll
        for (int m = 0; m < 3; ++m) {
            xf[4 + 2 * m] = px[m] - px[j];
            xf[5 + 2 * m] = py[m] - py[j];
        }
        const int a = o0[j], c2 = o1[j];
        xf[10] = px[a]  - px[j]; xf[11] = py[a]  - py[j];
        xf[12] = px[c2] - px[j]; xf[13] = py[c2] - py[j];
    }
}

// ================= K1: GAT, fully independent waves =================
// One thread = one (sample, graph), ALL 16 channels (8x f32x2 packed).
// NO LDS, NO barrier, NO exchange. g = wave&1 -> uniform branch + scalar weights.
// Register discipline: pass 1 builds xl only (48 packed regs); pass 2 rebuilds
// xf per source node i, builds xr_i transiently, folds into lp, discards.
__global__ __launch_bounds__(256)
void gat_kernel(
    const float* __restrict__ agent_pos, const float* __restrict__ agent_vel,
    const float* __restrict__ rel_lm, const float* __restrict__ other_pos,
    const float* __restrict__ lm_pos,
    const float* __restrict__ Wl, const float* __restrict__ bl,
    const float* __restrict__ Wr, const float* __restrict__ br,
    const float* __restrict__ We, const float* __restrict__ att,
    const float* __restrict__ bias,
    char* __restrict__ hbase, long hstride, int Btot)
{
    const int tid  = threadIdx.x;
    const int lane = tid & 63;
    const int w    = tid >> 6;
    const int g    = __builtin_amdgcn_readfirstlane(w & 1);
    const int sgrp = w >> 1;                     // 0..1: which 64-sample group
    int b = blockIdx.x * 128 + sgrp * 64 + lane;
    if (b >= Btot) b = Btot - 1;

    const int o0[3] = {1, 0, 0};
    const int o1[3] = {2, 2, 1};

    // ---- positions (uniform branch) ----
    float px[3], py[3];
    if (g == 0) {
        const float2* ap = reinterpret_cast<const float2*>(agent_pos + b * 6);
#pragma unroll
        for (int j = 0; j < 3; ++j) { px[j] = ap[j].x; py[j] = ap[j].y; }
    } else {
        const float2* lp2 = reinterpret_cast<const float2*>(lm_pos + b * 18);
#pragma unroll
        for (int m = 0; m < 3; ++m) { px[m] = lp2[m].x; py[m] = lp2[m].y; }
    }

    // ---- pairwise distances ----
    float d01, d02, d12;
    {
        float dx, dy;
        dx = px[0] - px[1]; dy = py[0] - py[1]; d01 = sqrtf(dx * dx + dy * dy);
        dx = px[0] - px[2]; dy = py[0] - py[2]; d02 = sqrtf(dx * dx + dy * dy);
        dx = px[1] - px[2]; dy = py[1] - py[2]; d12 = sqrtf(dx * dx + dy * dy);
    }

    // ---- pass 1: xl[3][16 ch] only ----
    f32x2 xl[3][8];
#pragma unroll
    for (int j = 0; j < 3; ++j) {
        float xf[14];
        build_xf(g, j, b, px, py, agent_vel, rel_lm, other_pos, xf);
#pragma unroll
        for (int cc = 0; cc < 8; ++cc) xl[j][cc] = ld2(bl + cc * 2);
#pragma unroll
        for (int k = 0; k < 14; ++k) {
            f32x2 xk = splat2(xf[k]);
#pragma unroll
            for (int cc = 0; cc < 8; ++cc)
                xl[j][cc] = pk_fma(xk, ld2(Wl + k * 16 + cc * 2), xl[j][cc]);
        }
    }

    // ---- pass 2: per source-target? build xr_i transiently, fold into lp ----
    float lp[9];
#pragma unroll
    for (int i = 0; i < 3; ++i) {
        float xf[14];
        build_xf(g, i, b, px, py, agent_vel, rel_lm, other_pos, xf);
        f32x2 xr[8];
#pragma unroll
        for (int cc = 0; cc < 8; ++cc) xr[cc] = ld2(br + cc * 2);
#pragma unroll
        for (int k = 0; k < 14; ++k) {
            f32x2 xk = splat2(xf[k]);
#pragma unroll
            for (int cc = 0; cc < 8; ++cc)
                xr[cc] = pk_fma(xk, ld2(Wr + k * 16 + cc * 2), xr[cc]);
        }
        // lp[j -> i] for all 3 sources j (xr_i is the TARGET transform here:
        // logits[j][i] = att . leaky(xl[j] + xr[i] + attr[j][i] @ We))
#pragma unroll
        for (int j = 0; j < 3; ++j) {
            float axv, ayv, adv;
            if (i == j) {
                const int a = o0[i], c2 = o1[i];
                axv = 0.5f * (px[a] + px[c2]) - px[i];
                ayv = 0.5f * (py[a] + py[c2]) - py[i];
                const float dA = (i == 0) ? d01 : ((i == 1) ? d01 : d02);
                const float dB = (i == 0) ? d02 : ((i == 1) ? d12 : d12);
                adv = 0.5f * (dA + dB);
            } else {
                axv = px[j] - px[i];
                ayv = py[j] - py[i];
                adv = ((i == 0 && j == 1) || (i == 1 && j == 0)) ? d01
                    : ((i == 0 && j == 2) || (i == 2 && j == 0)) ? d02 : d12;
            }
            f32x2 vax = splat2(axv), vay = splat2(ayv), vad = splat2(adv);
            f32x2 acc = {0.f, 0.f};
#pragma unroll
            for (int cc = 0; cc < 8; ++cc) {
                f32x2 gg = xl[j][cc] + xr[cc];
                gg = pk_fma(vax, ld2(We + cc * 2), gg);
                gg = pk_fma(vay, ld2(We + 16 + cc * 2), gg);
                gg = pk_fma(vad, ld2(We + 32 + cc * 2), gg);
                f32x2 lk = pk_max(gg, gg * splat2(NEG_SLOPE));
                acc = pk_fma(lk, ld2(att + cc * 2), acc);
            }
            lp[j * 3 + i] = acc.x + acc.y;
        }
    }

    // ---- softmax per target (logits O(10), no max-sub) + pooled relu-sum ----
    f32x2 hs[8] = {{0,0},{0,0},{0,0},{0,0},{0,0},{0,0},{0,0},{0,0}};
    const f32x2 zero2 = {0.f, 0.f};
#pragma unroll
    for (int i = 0; i < 3; ++i) {
        float e0 = __expf(lp[i]);
        float e1 = __expf(lp[3 + i]);
        float e2 = __expf(lp[6 + i]);
        float inv = __builtin_amdgcn_rcpf(e0 + e1 + e2);
        f32x2 a0 = splat2(e0 * inv), a1 = splat2(e1 * inv), a2 = splat2(e2 * inv);
#pragma unroll
        for (int cc = 0; cc < 8; ++cc) {
            f32x2 v = pk_fma(a0, xl[0][cc],
                      pk_fma(a1, xl[1][cc],
                      pk_fma(a2, xl[2][cc], ld2(bias + cc * 2))));
            hs[cc] += pk_max(v, zero2);
        }
    }

    // ---- store pooled h: 16 ch bf16 = 32B at offset g*32 of the 64B row ----
    bf16x8 hv0, hv1;
#pragma unroll
    for (int cc = 0; cc < 4; ++cc) {
        hv0[cc * 2 + 0] = (__bf16)hs[cc].x;
        hv0[cc * 2 + 1] = (__bf16)hs[cc].y;
        hv1[cc * 2 + 0] = (__bf16)hs[4 + cc].x;
        hv1[cc * 2 + 1] = (__bf16)hs[4 + cc].y;
    }
    char* p = hbase + (size_t)b * hstride + g * 32;
    *reinterpret_cast<bf16x8*>(p)      = hv0;
    *reinterpret_cast<bf16x8*>(p + 16) = hv1;
}

// ================= K2: MLP via MFMA 16x16x32 bf16 (validated R8/R9) =================
#define TPW 2
__global__ __launch_bounds__(256)
void mlp_kernel(const char* __restrict__ hbase, long hstride,
                const bf16x8* __restrict__ W1F, const bf16x8* __restrict__ W2F,
                const float* __restrict__ b1, const float* __restrict__ b2,
                float* __restrict__ out, int nTiles)
{
    __shared__ alignas(16) __bf16 lds_z[4][16][136];   // per-wave, stride 272B

    const int tid  = threadIdx.x;
    const int lane = tid & 63;
    const int wu   = __builtin_amdgcn_readfirstlane(tid >> 6);
    const int l15  = lane & 15;
    const int l4   = lane >> 4;
    const f32x4 zero4 = {0.f, 0.f, 0.f, 0.f};

    bf16x8 w1f[8], w2f[8];
#pragma unroll
    for (int n = 0; n < 8; ++n) w1f[n] = W1F[(n << 6) | lane];
#pragma unroll
    for (int t = 0; t < 8; ++t) w2f[t] = W2F[(t << 6) | lane];
    float b1v[8], b2v[2];
#pragma unroll
    for (int n = 0; n < 8; ++n) b1v[n] = b1[n * 16 + l15];
#pragma unroll
    for (int nn = 0; nn < 2; ++nn) b2v[nn] = b2[nn * 16 + l15];

    const int tile0 = (blockIdx.x * 4 + wu) * TPW;
#pragma unroll
    for (int tt = 0; tt < TPW; ++tt) {
        const int tile = tile0 + tt;
        if (tile >= nTiles) break;
        const int row0 = tile * 16;

        bf16x8 a1 = *reinterpret_cast<const bf16x8*>(
            hbase + (size_t)(row0 + l15) * hstride + l4 * 16);
        f32x4 acc[8];
#pragma unroll
        for (int n = 0; n < 8; ++n)
            acc[n] = __builtin_amdgcn_mfma_f32_16x16x32_bf16(a1, w1f[n], zero4, 0, 0, 0);

#pragma unroll
        for (int r = 0; r < 4; ++r) {
            bf16x8 zv;
#pragma unroll
            for (int n = 0; n < 8; ++n) zv[n] = (__bf16)relu_f(acc[n][r] + b1v[n]);
            *reinterpret_cast<bf16x8*>(&lds_z[wu][l4 * 4 + r][l15 * 8]) = zv;
        }

        f32x4 o2[2] = {zero4, zero4};
#pragma unroll
        for (int ks = 0; ks < 4; ++ks) {
            bf16x8 a2 = *reinterpret_cast<const bf16x8*>(&lds_z[wu][l15][ks * 32 + l4 * 8]);
#pragma unroll
            for (int nn = 0; nn < 2; ++nn)
                o2[nn] = __builtin_amdgcn_mfma_f32_16x16x32_bf16(a2, w2f[ks * 2 + nn], o2[nn], 0, 0, 0);
        }

#pragma unroll
        for (int nn = 0; nn < 2; ++nn) {
#pragma unroll
            for (int r = 0; r < 4; ++r) {
                int row = row0 + l4 * 4 + r;
                out[(size_t)row * 32 + nn * 16 + l15] = o2[nn][r] + b2v[nn];
            }
        }
    }
}

extern "C" void kernel_launch(void* const* d_in, const int* in_sizes, int n_in,
                              void* d_out, int out_size, void* d_ws, size_t ws_size,
                              hipStream_t stream) {
    const float* agent_pos = (const float*)d_in[0];
    const float* agent_vel = (const float*)d_in[1];
    const float* rel_lm    = (const float*)d_in[2];
    const float* other_pos = (const float*)d_in[3];
    const float* lm_pos    = (const float*)d_in[4];
    const float* Wl   = (const float*)d_in[5];
    const float* bl   = (const float*)d_in[6];
    const float* Wr   = (const float*)d_in[7];
    const float* br   = (const float*)d_in[8];
    const float* We   = (const float*)d_in[9];
    const float* att  = (const float*)d_in[10];
    const float* bias = (const float*)d_in[11];
    const float* W1   = (const float*)d_in[12];
    const float* b1   = (const float*)d_in[13];
    const float* W2   = (const float*)d_in[14];
    const float* b2   = (const float*)d_in[15];
    float* out = (float*)d_out;

    int B = in_sizes[0] / 6;                       // agent_pos is [B,3,2]

    __bf16* W1F = (__bf16*)d_ws;                   // 8 KB
    __bf16* W2F = (__bf16*)((char*)d_ws + 8192);   // 8 KB

    size_t need = 16384 + (size_t)B * 64;
    char* hbase; long hstride;
    if (ws_size >= need) { hbase = (char*)d_ws + 16384; hstride = 64; }
    else                 { hbase = (char*)out + 64;     hstride = 128; }

    prep_weights<<<32, 256, 0, stream>>>(W1, W2, W1F, W2F);

    int grid1 = (B + 127) / 128;
    gat_kernel<<<grid1, 256, 0, stream>>>(
        agent_pos, agent_vel, rel_lm, other_pos, lm_pos,
        Wl, bl, Wr, br, We, att, bias, hbase, hstride, B);

    int nTiles = (B + 15) / 16;
    int grid2 = (nTiles + 4 * TPW - 1) / (4 * TPW);
    mlp_kernel<<<grid2, 256, 0, stream>>>(
        hbase, hstride, (const bf16x8*)W1F, (const bf16x8*)W2F, b1, b2, out, nTiles);
}

// Round 11
// 43.888 us; speedup vs baseline: 1.2170x; 1.2170x over previous
//
#include <hip/hip_runtime.h>

#define NEG_SLOPE 0.2f

typedef __bf16 bf16x8 __attribute__((ext_vector_type(8)));
typedef float  f32x4  __attribute__((ext_vector_type(4)));
typedef float  f32x2  __attribute__((ext_vector_type(2)));

__device__ __forceinline__ float relu_f(float v) { return v > 0.f ? v : 0.f; }
__device__ __forceinline__ f32x2 pk_fma(f32x2 a, f32x2 b, f32x2 c) { return __builtin_elementwise_fma(a, b, c); }
__device__ __forceinline__ f32x2 pk_max(f32x2 a, f32x2 b) { return __builtin_elementwise_max(a, b); }
__device__ __forceinline__ f32x2 splat2(float s) { f32x2 r = {s, s}; return r; }
__device__ __forceinline__ f32x2 ld2(const float* p) { return *reinterpret_cast<const f32x2*>(p); }

// ---------------- prep: W1/W2 -> bf16 MFMA B-fragment order (validated R7-R10) ----------------
__global__ __launch_bounds__(256)
void prep_weights(const float* __restrict__ W1, const float* __restrict__ W2,
                  __bf16* __restrict__ W1F, __bf16* __restrict__ W2F)
{
    int idx = blockIdx.x * 256 + threadIdx.x;   // 0..8191
    int half = idx >> 12;                        // 0: W1, 1: W2
    int e    = idx & 4095;
    int j   = e & 7;
    int l   = (e >> 3) & 63;
    int t   = e >> 9;                            // 0..7
    int l15 = l & 15;
    int l4  = l >> 4;
    if (half == 0) {
        W1F[e] = (__bf16)W1[(l4 * 8 + j) * 128 + t * 16 + l15];
    } else {
        int ks = t >> 1, nn = t & 1;
        W2F[e] = (__bf16)W2[(j * 16 + ks * 4 + l4) * 32 + nn * 16 + l15];
    }
}

// ================= K1: GAT, R9 structure + 2 samples/thread =================
// Block = 256 threads = 4 waves, 128 samples/block.
// wave w -> g = w&1 (graph), ch = (w>>1)&1 (channel half, 8 ch = 4 f32x2);
// lane = sample-in-group; each thread carries samples bA = blk*128+lane and
// bB = bA+64 so every uniform weight s_load feeds TWO samples (scalar traffic
// per sample halves) and ILP doubles. One barrier (logit-partial exchange).
__global__ __launch_bounds__(256)
void gat_kernel(
    const float* __restrict__ agent_pos, const float* __restrict__ agent_vel,
    const float* __restrict__ rel_lm, const float* __restrict__ other_pos,
    const float* __restrict__ lm_pos,
    const float* __restrict__ Wl, const float* __restrict__ bl,
    const float* __restrict__ Wr, const float* __restrict__ br,
    const float* __restrict__ We, const float* __restrict__ att,
    const float* __restrict__ bias,
    char* __restrict__ hbase, long hstride, int Btot)
{
    __shared__ float lds_lp[2][2][128][9];   // [g][ch][sample-in-block][edge]

    const int tid  = threadIdx.x;
    const int lane = tid & 63;
    const int w    = tid >> 6;
    const int g    = __builtin_amdgcn_readfirstlane(w & 1);
    const int ch   = __builtin_amdgcn_readfirstlane((w >> 1) & 1);
    const int CB   = ch * 8;

    int bA = blockIdx.x * 128 + lane;
    if (bA >= Btot) bA = Btot - 1;
    int bB = bA + 64;
    if (bB >= Btot) bB = Btot - 1;

    const int o0[3] = {1, 0, 0};
    const int o1[3] = {2, 2, 1};

    // ---- positions (uniform branch) ----
    float pxA[3], pyA[3], pxB[3], pyB[3];
    if (g == 0) {
        const float2* apA = reinterpret_cast<const float2*>(agent_pos + bA * 6);
        const float2* apB = reinterpret_cast<const float2*>(agent_pos + bB * 6);
#pragma unroll
        for (int j = 0; j < 3; ++j) {
            pxA[j] = apA[j].x; pyA[j] = apA[j].y;
            pxB[j] = apB[j].x; pyB[j] = apB[j].y;
        }
    } else {
        const float2* lpA = reinterpret_cast<const float2*>(lm_pos + bA * 18);
        const float2* lpB = reinterpret_cast<const float2*>(lm_pos + bB * 18);
#pragma unroll
        for (int m = 0; m < 3; ++m) {
            pxA[m] = lpA[m].x; pyA[m] = lpA[m].y;
            pxB[m] = lpB[m].x; pyB[m] = lpB[m].y;
        }
    }

    // ---- pairwise distances (per sample) ----
    float dA01, dA02, dA12, dB01, dB02, dB12;
    {
        float dx, dy;
        dx = pxA[0]-pxA[1]; dy = pyA[0]-pyA[1]; dA01 = sqrtf(dx*dx+dy*dy);
        dx = pxA[0]-pxA[2]; dy = pyA[0]-pyA[2]; dA02 = sqrtf(dx*dx+dy*dy);
        dx = pxA[1]-pxA[2]; dy = pyA[1]-pyA[2]; dA12 = sqrtf(dx*dx+dy*dy);
        dx = pxB[0]-pxB[1]; dy = pyB[0]-pyB[1]; dB01 = sqrtf(dx*dx+dy*dy);
        dx = pxB[0]-pxB[2]; dy = pyB[0]-pyB[2]; dB02 = sqrtf(dx*dx+dy*dy);
        dx = pxB[1]-pxB[2]; dy = pyB[1]-pyB[2]; dB12 = sqrtf(dx*dx+dy*dy);
    }

    // ---- xl/xr for my 8 channels, both samples (each weight ld2 used 2x) ----
    f32x2 xlA[3][4], xrA[3][4], xlB[3][4], xrB[3][4];
#pragma unroll
    for (int j = 0; j < 3; ++j) {
        float xfA[14], xfB[14];
        if (g == 0) {
            const float2 velA = reinterpret_cast<const float2*>(agent_vel + bA * 6)[j];
            const float2* rlA = reinterpret_cast<const float2*>(rel_lm + bA * 18 + j * 6);
            const float4 opA  = reinterpret_cast<const float4*>(other_pos + bA * 12)[j];
            xfA[0]=pxA[j]; xfA[1]=pyA[j]; xfA[2]=velA.x; xfA[3]=velA.y;
            xfA[4]=rlA[0].x; xfA[5]=rlA[0].y; xfA[6]=rlA[1].x; xfA[7]=rlA[1].y;
            xfA[8]=rlA[2].x; xfA[9]=rlA[2].y;
            xfA[10]=opA.x; xfA[11]=opA.y; xfA[12]=opA.z; xfA[13]=opA.w;
            const float2 velB = reinterpret_cast<const float2*>(agent_vel + bB * 6)[j];
            const float2* rlB = reinterpret_cast<const float2*>(rel_lm + bB * 18 + j * 6);
            const float4 opB  = reinterpret_cast<const float4*>(other_pos + bB * 12)[j];
            xfB[0]=pxB[j]; xfB[1]=pyB[j]; xfB[2]=velB.x; xfB[3]=velB.y;
            xfB[4]=rlB[0].x; xfB[5]=rlB[0].y; xfB[6]=rlB[1].x; xfB[7]=rlB[1].y;
            xfB[8]=rlB[2].x; xfB[9]=rlB[2].y;
            xfB[10]=opB.x; xfB[11]=opB.y; xfB[12]=opB.z; xfB[13]=opB.w;
        } else {
            xfA[0]=pxA[j]; xfA[1]=pyA[j]; xfA[2]=0.f; xfA[3]=0.f;
            xfB[0]=pxB[j]; xfB[1]=pyB[j]; xfB[2]=0.f; xfB[3]=0.f;
#pragma unroll
            for (int m = 0; m < 3; ++m) {
                xfA[4+2*m] = pxA[m]-pxA[j]; xfA[5+2*m] = pyA[m]-pyA[j];
                xfB[4+2*m] = pxB[m]-pxB[j]; xfB[5+2*m] = pyB[m]-pyB[j];
            }
            const int a = o0[j], c2 = o1[j];
            xfA[10]=pxA[a]-pxA[j];  xfA[11]=pyA[a]-pyA[j];
            xfA[12]=pxA[c2]-pxA[j]; xfA[13]=pyA[c2]-pyA[j];
            xfB[10]=pxB[a]-pxB[j];  xfB[11]=pyB[a]-pyB[j];
            xfB[12]=pxB[c2]-pxB[j]; xfB[13]=pyB[c2]-pyB[j];
        }
#pragma unroll
        for (int cc = 0; cc < 4; ++cc) {
            f32x2 vbl = ld2(bl + CB + cc * 2), vbr = ld2(br + CB + cc * 2);
            xlA[j][cc] = vbl; xlB[j][cc] = vbl;
            xrA[j][cc] = vbr; xrB[j][cc] = vbr;
        }
#pragma unroll
        for (int k = 0; k < 14; ++k) {
            f32x2 xkA = splat2(xfA[k]), xkB = splat2(xfB[k]);
#pragma unroll
            for (int cc = 0; cc < 4; ++cc) {
                f32x2 wl = ld2(Wl + k * 16 + CB + cc * 2);
                f32x2 wr = ld2(Wr + k * 16 + CB + cc * 2);
                xlA[j][cc] = pk_fma(xkA, wl, xlA[j][cc]);
                xlB[j][cc] = pk_fma(xkB, wl, xlB[j][cc]);
                xrA[j][cc] = pk_fma(xkA, wr, xrA[j][cc]);
                xrB[j][cc] = pk_fma(xkB, wr, xrB[j][cc]);
            }
        }
    }

    // ---- logit partials, 9 edges, both samples (We/att ld2 shared) ----
    float lpA[9], lpB[9];
#pragma unroll
    for (int i = 0; i < 3; ++i) {
#pragma unroll
        for (int j = 0; j < 3; ++j) {
            float axA, ayA, adA, axB, ayB, adB;
            if (i == j) {
                const int a = o0[i], c2 = o1[i];
                axA = 0.5f*(pxA[a]+pxA[c2]) - pxA[i];
                ayA = 0.5f*(pyA[a]+pyA[c2]) - pyA[i];
                axB = 0.5f*(pxB[a]+pxB[c2]) - pxB[i];
                ayB = 0.5f*(pyB[a]+pyB[c2]) - pyB[i];
                const float dAa = (i==0)?dA01:((i==1)?dA01:dA02);
                const float dAb = (i==0)?dA02:((i==1)?dA12:dA12);
                const float dBa = (i==0)?dB01:((i==1)?dB01:dB02);
                const float dBb = (i==0)?dB02:((i==1)?dB12:dB12);
                adA = 0.5f*(dAa+dAb); adB = 0.5f*(dBa+dBb);
            } else {
                axA = pxA[j]-pxA[i]; ayA = pyA[j]-pyA[i];
                axB = pxB[j]-pxB[i]; ayB = pyB[j]-pyB[i];
                bool e01 = (i==0&&j==1)||(i==1&&j==0);
                bool e02 = (i==0&&j==2)||(i==2&&j==0);
                adA = e01 ? dA01 : (e02 ? dA02 : dA12);
                adB = e01 ? dB01 : (e02 ? dB02 : dB12);
            }
            f32x2 vaxA = splat2(axA), vayA = splat2(ayA), vadA = splat2(adA);
            f32x2 vaxB = splat2(axB), vayB = splat2(ayB), vadB = splat2(adB);
            f32x2 accA = {0.f, 0.f}, accB = {0.f, 0.f};
#pragma unroll
            for (int cc = 0; cc < 4; ++cc) {
                f32x2 we0 = ld2(We + CB + cc * 2);
                f32x2 we1 = ld2(We + 16 + CB + cc * 2);
                f32x2 we2 = ld2(We + 32 + CB + cc * 2);
                f32x2 vat = ld2(att + CB + cc * 2);
                f32x2 gA = xlA[j][cc] + xrA[i][cc];
                gA = pk_fma(vaxA, we0, gA);
                gA = pk_fma(vayA, we1, gA);
                gA = pk_fma(vadA, we2, gA);
                f32x2 lkA = pk_max(gA, gA * splat2(NEG_SLOPE));
                accA = pk_fma(lkA, vat, accA);
                f32x2 gB = xlB[j][cc] + xrB[i][cc];
                gB = pk_fma(vaxB, we0, gB);
                gB = pk_fma(vayB, we1, gB);
                gB = pk_fma(vadB, we2, gB);
                f32x2 lkB = pk_max(gB, gB * splat2(NEG_SLOPE));
                accB = pk_fma(lkB, vat, accB);
            }
            lpA[j*3+i] = accA.x + accA.y;
            lpB[j*3+i] = accB.x + accB.y;
        }
    }

    // ---- exchange partials with sibling channel-half ----
#pragma unroll
    for (int e = 0; e < 9; ++e) {
        lds_lp[g][ch][lane][e]      = lpA[e];
        lds_lp[g][ch][64 + lane][e] = lpB[e];
    }
    __syncthreads();    // the only barrier

    float lgA[9], lgB[9];
#pragma unroll
    for (int e = 0; e < 9; ++e) {
        lgA[e] = lpA[e] + lds_lp[g][1 - ch][lane][e];
        lgB[e] = lpB[e] + lds_lp[g][1 - ch][64 + lane][e];
    }

    // ---- softmax per target (logits O(10), no max-sub) + pooled relu-sum ----
    f32x2 hsA[4] = {{0,0},{0,0},{0,0},{0,0}};
    f32x2 hsB[4] = {{0,0},{0,0},{0,0},{0,0}};
    const f32x2 zero2 = {0.f, 0.f};
#pragma unroll
    for (int i = 0; i < 3; ++i) {
        float eA0 = __expf(lgA[i]), eA1 = __expf(lgA[3+i]), eA2 = __expf(lgA[6+i]);
        float eB0 = __expf(lgB[i]), eB1 = __expf(lgB[3+i]), eB2 = __expf(lgB[6+i]);
        float invA = __builtin_amdgcn_rcpf(eA0 + eA1 + eA2);
        float invB = __builtin_amdgcn_rcpf(eB0 + eB1 + eB2);
        f32x2 aA0 = splat2(eA0*invA), aA1 = splat2(eA1*invA), aA2 = splat2(eA2*invA);
        f32x2 aB0 = splat2(eB0*invB), aB1 = splat2(eB1*invB), aB2 = splat2(eB2*invB);
#pragma unroll
        for (int cc = 0; cc < 4; ++cc) {
            f32x2 vb = ld2(bias + CB + cc * 2);
            f32x2 vA = pk_fma(aA0, xlA[0][cc],
                       pk_fma(aA1, xlA[1][cc],
                       pk_fma(aA2, xlA[2][cc], vb)));
            hsA[cc] += pk_max(vA, zero2);
            f32x2 vB = pk_fma(aB0, xlB[0][cc],
                       pk_fma(aB1, xlB[1][cc],
                       pk_fma(aB2, xlB[2][cc], vb)));
            hsB[cc] += pk_max(vB, zero2);
        }
    }

    // ---- store pooled h (bf16x8 = my 8 channels) per sample ----
    bf16x8 hvA, hvB;
#pragma unroll
    for (int cc = 0; cc < 4; ++cc) {
        hvA[cc*2+0] = (__bf16)hsA[cc].x; hvA[cc*2+1] = (__bf16)hsA[cc].y;
        hvB[cc*2+0] = (__bf16)hsB[cc].x; hvB[cc*2+1] = (__bf16)hsB[cc].y;
    }
    *reinterpret_cast<bf16x8*>(hbase + (size_t)bA * hstride + (g*16+CB)*2) = hvA;
    *reinterpret_cast<bf16x8*>(hbase + (size_t)bB * hstride + (g*16+CB)*2) = hvB;
}

// ================= K2: MLP via MFMA 16x16x32 bf16 (validated R8-R10), TPW=4 =================
#define TPW 4
__global__ __launch_bounds__(256)
void mlp_kernel(const char* __restrict__ hbase, long hstride,
                const bf16x8* __restrict__ W1F, const bf16x8* __restrict__ W2F,
                const float* __restrict__ b1, const float* __restrict__ b2,
                float* __restrict__ out, int nTiles)
{
    __shared__ alignas(16) __bf16 lds_z[4][16][136];   // per-wave, stride 272B

    const int tid  = threadIdx.x;
    const int lane = tid & 63;
    const int wu   = __builtin_amdgcn_readfirstlane(tid >> 6);
    const int l15  = lane & 15;
    const int l4   = lane >> 4;
    const f32x4 zero4 = {0.f, 0.f, 0.f, 0.f};

    bf16x8 w1f[8], w2f[8];
#pragma unroll
    for (int n = 0; n < 8; ++n) w1f[n] = W1F[(n << 6) | lane];
#pragma unroll
    for (int t = 0; t < 8; ++t) w2f[t] = W2F[(t << 6) | lane];
    float b1v[8], b2v[2];
#pragma unroll
    for (int n = 0; n < 8; ++n) b1v[n] = b1[n * 16 + l15];
#pragma unroll
    for (int nn = 0; nn < 2; ++nn) b2v[nn] = b2[nn * 16 + l15];

    const int tile0 = (blockIdx.x * 4 + wu) * TPW;
#pragma unroll
    for (int tt = 0; tt < TPW; ++tt) {
        const int tile = tile0 + tt;
        if (tile >= nTiles) break;
        const int row0 = tile * 16;

        bf16x8 a1 = *reinterpret_cast<const bf16x8*>(
            hbase + (size_t)(row0 + l15) * hstride + l4 * 16);
        f32x4 acc[8];
#pragma unroll
        for (int n = 0; n < 8; ++n)
            acc[n] = __builtin_amdgcn_mfma_f32_16x16x32_bf16(a1, w1f[n], zero4, 0, 0, 0);

#pragma unroll
        for (int r = 0; r < 4; ++r) {
            bf16x8 zv;
#pragma unroll
            for (int n = 0; n < 8; ++n) zv[n] = (__bf16)relu_f(acc[n][r] + b1v[n]);
            *reinterpret_cast<bf16x8*>(&lds_z[wu][l4 * 4 + r][l15 * 8]) = zv;
        }

        f32x4 o2[2] = {zero4, zero4};
#pragma unroll
        for (int ks = 0; ks < 4; ++ks) {
            bf16x8 a2 = *reinterpret_cast<const bf16x8*>(&lds_z[wu][l15][ks * 32 + l4 * 8]);
#pragma unroll
            for (int nn = 0; nn < 2; ++nn)
                o2[nn] = __builtin_amdgcn_mfma_f32_16x16x32_bf16(a2, w2f[ks * 2 + nn], o2[nn], 0, 0, 0);
        }

#pragma unroll
        for (int nn = 0; nn < 2; ++nn) {
#pragma unroll
            for (int r = 0; r < 4; ++r) {
                int row = row0 + l4 * 4 + r;
                out[(size_t)row * 32 + nn * 16 + l15] = o2[nn][r] + b2v[nn];
            }
        }
    }
}

extern "C" void kernel_launch(void* const* d_in, const int* in_sizes, int n_in,
                              void* d_out, int out_size, void* d_ws, size_t ws_size,
                              hipStream_t stream) {
    const float* agent_pos = (const float*)d_in[0];
    const float* agent_vel = (const float*)d_in[1];
    const float* rel_lm    = (const float*)d_in[2];
    const float* other_pos = (const float*)d_in[3];
    const float* lm_pos    = (const float*)d_in[4];
    const float* Wl   = (const float*)d_in[5];
    const float* bl   = (const float*)d_in[6];
    const float* Wr   = (const float*)d_in[7];
    const float* br   = (const float*)d_in[8];
    const float* We   = (const float*)d_in[9];
    const float* att  = (const float*)d_in[10];
    const float* bias = (const float*)d_in[11];
    const float* W1   = (const float*)d_in[12];
    const float* b1   = (const float*)d_in[13];
    const float* W2   = (const float*)d_in[14];
    const float* b2   = (const float*)d_in[15];
    float* out = (float*)d_out;

    int B = in_sizes[0] / 6;                       // agent_pos is [B,3,2]

    __bf16* W1F = (__bf16*)d_ws;                   // 8 KB
    __bf16* W2F = (__bf16*)((char*)d_ws + 8192);   // 8 KB

    size_t need = 16384 + (size_t)B * 64;
    char* hbase; long hstride;
    if (ws_size >= need) { hbase = (char*)d_ws + 16384; hstride = 64; }
    else                 { hbase = (char*)out + 64;     hstride = 128; }

    prep_weights<<<32, 256, 0, stream>>>(W1, W2, W1F, W2F);

    int grid1 = (B + 127) / 128;
    gat_kernel<<<grid1, 256, 0, stream>>>(
        agent_pos, agent_vel, rel_lm, other_pos, lm_pos,
        Wl, bl, Wr, br, We, att, bias, hbase, hstride, B);

    int nTiles = (B + 15) / 16;
    int grid2 = (nTiles + 4 * TPW - 1) / (4 * TPW);
    mlp_kernel<<<grid2, 256, 0, stream>>>(
        hbase, hstride, (const bf16x8*)W1F, (const bf16x8*)W2F, b1, b2, out, nTiles);
}

// Round 13
// 42.123 us; speedup vs baseline: 1.2680x; 1.0419x over previous
//
#include <hip/hip_runtime.h>

#define NEG_SLOPE 0.2f

typedef __bf16 bf16x8 __attribute__((ext_vector_type(8)));
typedef float  f32x4  __attribute__((ext_vector_type(4)));
typedef float  f32x2  __attribute__((ext_vector_type(2)));

__device__ __forceinline__ float relu_f(float v) { return v > 0.f ? v : 0.f; }
__device__ __forceinline__ f32x2 pk_fma(f32x2 a, f32x2 b, f32x2 c) { return __builtin_elementwise_fma(a, b, c); }
__device__ __forceinline__ f32x2 pk_max(f32x2 a, f32x2 b) { return __builtin_elementwise_max(a, b); }
__device__ __forceinline__ f32x2 splat2(float s) { f32x2 r = {s, s}; return r; }
__device__ __forceinline__ f32x2 ld2(const float* p) { return *reinterpret_cast<const f32x2*>(p); }

// ============ ONE fused kernel: GAT + MLP, no prep, no workspace ============
// Block = 256 threads = 4 waves, 64 samples.
// Phase 0: stage W1/W2 bf16 MFMA B-fragments into LDS (validated R7 layout) and
//          compute the g=1 reduced transform matrices WRED (landmark features
//          are LINEAR in the 6 position scalars -> x@Wl == p@WRED, exact algebra).
// Phase 1: GAT (validated R9): wave w -> g=w&1, ch=(w>>1)&1 (8 ch as 4 f32x2);
//          lane = sample. g=1 transform uses WRED: 6 FMAs/ch, no feature build.
// Phase 2: MLP via MFMA 16x16x32 bf16 (validated R8): wave wu owns samples
//          wu*16..wu*16+15. z gets its OWN [4][16][136] buffer (R12 bug: z was
//          overlaid on a 4608-bf16 region with stride 72 < needed 128 -> overlap).
// LDS: 2304 + 9216 + 5120 + 8192 + 8192 + 17408 = 50432 B -> 3 blocks/CU.
__global__ __launch_bounds__(256)
void scl_fused_kernel(
    const float* __restrict__ agent_pos, const float* __restrict__ agent_vel,
    const float* __restrict__ rel_lm, const float* __restrict__ other_pos,
    const float* __restrict__ lm_pos,
    const float* __restrict__ Wl, const float* __restrict__ bl,
    const float* __restrict__ Wr, const float* __restrict__ br,
    const float* __restrict__ We, const float* __restrict__ att,
    const float* __restrict__ bias,
    const float* __restrict__ W1, const float* __restrict__ b1,
    const float* __restrict__ W2, const float* __restrict__ b2,
    float* __restrict__ out, int Btot)
{
    __shared__ alignas(16) float  lds_wred[2][3][6][16];   // [side l/r][node j][pos k][ch]
    __shared__ alignas(16) float  lds_lp[2304];            // lp[2][2][64][9] f32
    __shared__ alignas(16) __bf16 lds_h[64][40];           // pooled GAT out
    __shared__ alignas(16) __bf16 lds_w1f[4096];           // W1 B-fragments
    __shared__ alignas(16) __bf16 lds_w2f[4096];           // W2 B-fragments (row-permuted)
    __shared__ alignas(16) __bf16 lds_z[4][16][136];       // per-wave z (R8 layout)

    const int tid  = threadIdx.x;
    const int lane = tid & 63;
    const int w    = tid >> 6;
    const int g    = __builtin_amdgcn_readfirstlane(w & 1);
    const int ch   = __builtin_amdgcn_readfirstlane((w >> 1) & 1);
    const int wu   = __builtin_amdgcn_readfirstlane(w);
    const int CB   = ch * 8;

    int b = blockIdx.x * 64 + lane;
    if (b >= Btot) b = Btot - 1;            // clamp reads; barriers stay uniform

    const int o0[3] = {1, 0, 0};
    const int o1[3] = {2, 2, 1};

    // ---------- phase 0a: stage W1/W2 fragments (consumed after B2) ----------
#pragma unroll
    for (int u = 0; u < 16; ++u) {
        int e  = u * 256 + tid;             // 0..4095
        int j  = e & 7, l = (e >> 3) & 63, t = e >> 9;
        int l15 = l & 15, l4 = l >> 4;
        lds_w1f[e] = (__bf16)W1[(l4 * 8 + j) * 128 + t * 16 + l15];
        int ks = t >> 1, nn = t & 1;
        lds_w2f[e] = (__bf16)W2[(j * 16 + ks * 4 + l4) * 32 + nn * 16 + l15];
    }
    // ---------- phase 0b: reduced g=1 transform matrices (exact algebra) ----
    if (tid < 192) {
#pragma unroll
        for (int q = 0; q < 3; ++q) {
            int e = tid * 3 + q;            // 0..575
            int c = e & 15;
            int r16 = e >> 4;               // (side*3+j)*6+k
            int k = r16 % 6, sj = r16 / 6, j = sj % 3, side = sj / 3;
            const float* Wm = side ? Wr : Wl;
            int m = k >> 1, isY = k & 1;
            float v = Wm[(4 + 2 * m + isY) * 16 + c];
            if (m == o0[j]) v += Wm[(10 + isY) * 16 + c];
            if (m == o1[j]) v += Wm[(12 + isY) * 16 + c];
            if (m == j)
                v += Wm[(0 + isY) * 16 + c] - Wm[(4 + isY) * 16 + c]
                   - Wm[(6 + isY) * 16 + c] - Wm[(8 + isY) * 16 + c]
                   - Wm[(10 + isY) * 16 + c] - Wm[(12 + isY) * 16 + c];
            lds_wred[side][j][k][c] = v;
        }
    }
    __syncthreads();    // B0: wred + fragments ready

    // ---------- phase 1: GAT ----------
    float px[3], py[3];
    f32x2 xl[3][4], xr[3][4];

    if (g == 0) {
        const float2* ap = reinterpret_cast<const float2*>(agent_pos + b * 6);
#pragma unroll
        for (int j = 0; j < 3; ++j) { px[j] = ap[j].x; py[j] = ap[j].y; }
#pragma unroll
        for (int j = 0; j < 3; ++j) {
            float xf[14];
            const float2 vel = reinterpret_cast<const float2*>(agent_vel + b * 6)[j];
            const float2* rl = reinterpret_cast<const float2*>(rel_lm + b * 18 + j * 6);
            const float4 op  = reinterpret_cast<const float4*>(other_pos + b * 12)[j];
            xf[0] = px[j]; xf[1] = py[j];
            xf[2] = vel.x; xf[3] = vel.y;
            xf[4] = rl[0].x; xf[5] = rl[0].y;
            xf[6] = rl[1].x; xf[7] = rl[1].y;
            xf[8] = rl[2].x; xf[9] = rl[2].y;
            xf[10] = op.x; xf[11] = op.y; xf[12] = op.z; xf[13] = op.w;
#pragma unroll
            for (int cc = 0; cc < 4; ++cc) {
                xl[j][cc] = ld2(bl + CB + cc * 2);
                xr[j][cc] = ld2(br + CB + cc * 2);
            }
#pragma unroll
            for (int k = 0; k < 14; ++k) {
                f32x2 xk = splat2(xf[k]);
#pragma unroll
                for (int cc = 0; cc < 4; ++cc) {
                    xl[j][cc] = pk_fma(xk, ld2(Wl + k * 16 + CB + cc * 2), xl[j][cc]);
                    xr[j][cc] = pk_fma(xk, ld2(Wr + k * 16 + CB + cc * 2), xr[j][cc]);
                }
            }
        }
    } else {
        const float2* lp2 = reinterpret_cast<const float2*>(lm_pos + b * 18);
#pragma unroll
        for (int m = 0; m < 3; ++m) { px[m] = lp2[m].x; py[m] = lp2[m].y; }
        float ps[6] = {px[0], py[0], px[1], py[1], px[2], py[2]};
#pragma unroll
        for (int j = 0; j < 3; ++j) {
#pragma unroll
            for (int cc = 0; cc < 4; ++cc) {
                xl[j][cc] = ld2(bl + CB + cc * 2);
                xr[j][cc] = ld2(br + CB + cc * 2);
            }
#pragma unroll
            for (int k = 0; k < 6; ++k) {
                f32x2 pk = splat2(ps[k]);
#pragma unroll
                for (int cc = 0; cc < 4; ++cc) {
                    xl[j][cc] = pk_fma(pk, ld2(&lds_wred[0][j][k][CB + cc * 2]), xl[j][cc]);
                    xr[j][cc] = pk_fma(pk, ld2(&lds_wred[1][j][k][CB + cc * 2]), xr[j][cc]);
                }
            }
        }
    }

    // ---- pairwise distances ----
    float d01, d02, d12;
    {
        float dx, dy;
        dx = px[0] - px[1]; dy = py[0] - py[1]; d01 = sqrtf(dx * dx + dy * dy);
        dx = px[0] - px[2]; dy = py[0] - py[2]; d02 = sqrtf(dx * dx + dy * dy);
        dx = px[1] - px[2]; dy = py[1] - py[2]; d12 = sqrtf(dx * dx + dy * dy);
    }

    // ---- logit partials over my 8 channels, all 9 edges ----
    float lp[9];
#pragma unroll
    for (int i = 0; i < 3; ++i) {
#pragma unroll
        for (int j = 0; j < 3; ++j) {
            float axv, ayv, adv;
            if (i == j) {
                const int a = o0[i], c2 = o1[i];
                axv = 0.5f * (px[a] + px[c2]) - px[i];
                ayv = 0.5f * (py[a] + py[c2]) - py[i];
                const float dA = (i == 0) ? d01 : ((i == 1) ? d01 : d02);
                const float dB = (i == 0) ? d02 : ((i == 1) ? d12 : d12);
                adv = 0.5f * (dA + dB);
            } else {
                axv = px[j] - px[i];
                ayv = py[j] - py[i];
                adv = ((i == 0 && j == 1) || (i == 1 && j == 0)) ? d01
                    : ((i == 0 && j == 2) || (i == 2 && j == 0)) ? d02 : d12;
            }
            f32x2 vax = splat2(axv), vay = splat2(ayv), vad = splat2(adv);
            f32x2 acc = {0.f, 0.f};
#pragma unroll
            for (int cc = 0; cc < 4; ++cc) {
                f32x2 gg = xl[j][cc] + xr[i][cc];
                gg = pk_fma(vax, ld2(We + CB + cc * 2), gg);
                gg = pk_fma(vay, ld2(We + 16 + CB + cc * 2), gg);
                gg = pk_fma(vad, ld2(We + 32 + CB + cc * 2), gg);
                f32x2 lk = pk_max(gg, gg * splat2(NEG_SLOPE));
                acc = pk_fma(lk, ld2(att + CB + cc * 2), acc);
            }
            lp[j * 3 + i] = acc.x + acc.y;
        }
    }

    // ---- exchange partials with sibling channel-half ----
#define LPX(gg, cc2, ss, ee) lds_lp[(((gg) * 2 + (cc2)) * 64 + (ss)) * 9 + (ee)]
#pragma unroll
    for (int e = 0; e < 9; ++e) LPX(g, ch, lane, e) = lp[e];
    __syncthreads();    // B1

    float lg[9];
#pragma unroll
    for (int e = 0; e < 9; ++e) lg[e] = lp[e] + LPX(g, 1 - ch, lane, e);

    // ---- softmax per target (logits O(10), no max-sub) + pooled relu-sum ----
    f32x2 hs[4] = {{0,0},{0,0},{0,0},{0,0}};
    const f32x2 zero2 = {0.f, 0.f};
#pragma unroll
    for (int i = 0; i < 3; ++i) {
        float e0 = __expf(lg[i]);
        float e1 = __expf(lg[3 + i]);
        float e2 = __expf(lg[6 + i]);
        float inv = __builtin_amdgcn_rcpf(e0 + e1 + e2);
        f32x2 a0 = splat2(e0 * inv), a1 = splat2(e1 * inv), a2 = splat2(e2 * inv);
#pragma unroll
        for (int cc = 0; cc < 4; ++cc) {
            f32x2 v = pk_fma(a0, xl[0][cc],
                      pk_fma(a1, xl[1][cc],
                      pk_fma(a2, xl[2][cc], ld2(bias + CB + cc * 2))));
            hs[cc] += pk_max(v, zero2);
        }
    }

    // ---- publish pooled h as bf16 into LDS ----
    {
        bf16x8 hv;
#pragma unroll
        for (int cc = 0; cc < 4; ++cc) {
            hv[cc * 2 + 0] = (__bf16)hs[cc].x;
            hv[cc * 2 + 1] = (__bf16)hs[cc].y;
        }
        *reinterpret_cast<bf16x8*>(&lds_h[lane][g * 16 + CB]) = hv;
    }
    __syncthreads();    // B2: h ready

    // ---------- phase 2: MLP via MFMA 16x16x32 bf16 (R8 layout) ----------
    const int l15 = lane & 15;
    const int l4  = lane >> 4;
    const f32x4 zero4 = {0.f, 0.f, 0.f, 0.f};

    float b1v[8], b2v[2];
#pragma unroll
    for (int n = 0; n < 8; ++n) b1v[n] = b1[n * 16 + l15];
#pragma unroll
    for (int nn = 0; nn < 2; ++nn) b2v[nn] = b2[nn * 16 + l15];

    // layer 1: z[16x128] = h[16x32] @ W1 + b1, relu
    bf16x8 a1 = *reinterpret_cast<const bf16x8*>(&lds_h[wu * 16 + l15][l4 * 8]);
    f32x4 acc[8];
#pragma unroll
    for (int n = 0; n < 8; ++n) {
        bf16x8 bfrag = *reinterpret_cast<const bf16x8*>(&lds_w1f[((n << 6) | lane) * 8]);
        acc[n] = __builtin_amdgcn_mfma_f32_16x16x32_bf16(a1, bfrag, zero4, 0, 0, 0);
    }
#pragma unroll
    for (int r = 0; r < 4; ++r) {
        bf16x8 zv;
#pragma unroll
        for (int n = 0; n < 8; ++n) zv[n] = (__bf16)relu_f(acc[n][r] + b1v[n]);
        *reinterpret_cast<bf16x8*>(&lds_z[wu][l4 * 4 + r][l15 * 8]) = zv;
    }

    // layer 2: o[16x32] = z @ W2 + b2 (same-wave z reuse, compiler waits lgkmcnt)
    f32x4 o2[2] = {zero4, zero4};
#pragma unroll
    for (int ks = 0; ks < 4; ++ks) {
        bf16x8 a2 = *reinterpret_cast<const bf16x8*>(&lds_z[wu][l15][ks * 32 + l4 * 8]);
#pragma unroll
        for (int nn = 0; nn < 2; ++nn) {
            bf16x8 bfrag = *reinterpret_cast<const bf16x8*>(&lds_w2f[(((ks * 2 + nn) << 6) | lane) * 8]);
            o2[nn] = __builtin_amdgcn_mfma_f32_16x16x32_bf16(a2, bfrag, o2[nn], 0, 0, 0);
        }
    }

    // store: lane holds o[l4*4+r][nn*16+l15]
#pragma unroll
    for (int nn = 0; nn < 2; ++nn) {
#pragma unroll
        for (int r = 0; r < 4; ++r) {
            int row = blockIdx.x * 64 + wu * 16 + l4 * 4 + r;
            if (row < Btot)
                out[(size_t)row * 32 + nn * 16 + l15] = o2[nn][r] + b2v[nn];
        }
    }
}

extern "C" void kernel_launch(void* const* d_in, const int* in_sizes, int n_in,
                              void* d_out, int out_size, void* d_ws, size_t ws_size,
                              hipStream_t stream) {
    const float* agent_pos = (const float*)d_in[0];
    const float* agent_vel = (const float*)d_in[1];
    const float* rel_lm    = (const float*)d_in[2];
    const float* other_pos = (const float*)d_in[3];
    const float* lm_pos    = (const float*)d_in[4];
    const float* Wl   = (const float*)d_in[5];
    const float* bl   = (const float*)d_in[6];
    const float* Wr   = (const float*)d_in[7];
    const float* br   = (const float*)d_in[8];
    const float* We   = (const float*)d_in[9];
    const float* att  = (const float*)d_in[10];
    const float* bias = (const float*)d_in[11];
    const float* W1   = (const float*)d_in[12];
    const float* b1   = (const float*)d_in[13];
    const float* W2   = (const float*)d_in[14];
    const float* b2   = (const float*)d_in[15];
    float* out = (float*)d_out;

    int B = in_sizes[0] / 6;                  // agent_pos is [B,3,2]
    int grid = (B + 63) / 64;
    scl_fused_kernel<<<grid, 256, 0, stream>>>(
        agent_pos, agent_vel, rel_lm, other_pos, lm_pos,
        Wl, bl, Wr, br, We, att, bias, W1, b1, W2, b2, out, B);
}

// Round 14
// 41.429 us; speedup vs baseline: 1.2892x; 1.0167x over previous
//
#include <hip/hip_runtime.h>

#define NEG_SLOPE 0.2f

typedef __bf16 bf16x8 __attribute__((ext_vector_type(8)));
typedef float  f32x4  __attribute__((ext_vector_type(4)));
typedef float  f32x2  __attribute__((ext_vector_type(2)));

__device__ __forceinline__ float relu_f(float v) { return v > 0.f ? v : 0.f; }
__device__ __forceinline__ f32x2 pk_fma(f32x2 a, f32x2 b, f32x2 c) { return __builtin_elementwise_fma(a, b, c); }
__device__ __forceinline__ f32x2 pk_max(f32x2 a, f32x2 b) { return __builtin_elementwise_max(a, b); }
__device__ __forceinline__ f32x2 splat2(float s) { f32x2 r = {s, s}; return r; }
__device__ __forceinline__ f32x2 ld2(const float* p) { return *reinterpret_cast<const f32x2*>(p); }

// ============ ONE fused kernel: GAT + MLP (R13 structure, s_load-reuse loops) ============
// Block = 256 threads = 4 waves, 64 samples.
// R14 change vs R13 (validated): loop order only. Transform is k-outer/j-inner so
// each Wl/Wr s_load serves all 3 nodes (670->224 s_loads/thread); logit loop is
// cc-outer/edge-inner with precomputed edge geometry (290->32); bias hoisted.
// LDS: wred 2304 + lp 9216 + h 5120 + w1f 8192 + w2f 8192 + z 17408 = 50432 B.
__global__ __launch_bounds__(256)
void scl_fused_kernel(
    const float* __restrict__ agent_pos, const float* __restrict__ agent_vel,
    const float* __restrict__ rel_lm, const float* __restrict__ other_pos,
    const float* __restrict__ lm_pos,
    const float* __restrict__ Wl, const float* __restrict__ bl,
    const float* __restrict__ Wr, const float* __restrict__ br,
    const float* __restrict__ We, const float* __restrict__ att,
    const float* __restrict__ bias,
    const float* __restrict__ W1, const float* __restrict__ b1,
    const float* __restrict__ W2, const float* __restrict__ b2,
    float* __restrict__ out, int Btot)
{
    __shared__ alignas(16) float  lds_wred[2][3][6][16];   // [side l/r][node j][pos k][ch]
    __shared__ alignas(16) float  lds_lp[2304];            // lp[2][2][64][9] f32
    __shared__ alignas(16) __bf16 lds_h[64][40];           // pooled GAT out
    __shared__ alignas(16) __bf16 lds_w1f[4096];           // W1 B-fragments
    __shared__ alignas(16) __bf16 lds_w2f[4096];           // W2 B-fragments (row-permuted)
    __shared__ alignas(16) __bf16 lds_z[4][16][136];       // per-wave z (R8 layout)

    const int tid  = threadIdx.x;
    const int lane = tid & 63;
    const int w    = tid >> 6;
    const int g    = __builtin_amdgcn_readfirstlane(w & 1);
    const int ch   = __builtin_amdgcn_readfirstlane((w >> 1) & 1);
    const int wu   = __builtin_amdgcn_readfirstlane(w);
    const int CB   = ch * 8;

    int b = blockIdx.x * 64 + lane;
    if (b >= Btot) b = Btot - 1;            // clamp reads; barriers stay uniform

    const int o0[3] = {1, 0, 0};
    const int o1[3] = {2, 2, 1};

    // ---------- phase 0a: stage W1/W2 fragments (consumed after B2) ----------
#pragma unroll
    for (int u = 0; u < 16; ++u) {
        int e  = u * 256 + tid;             // 0..4095
        int j  = e & 7, l = (e >> 3) & 63, t = e >> 9;
        int l15 = l & 15, l4 = l >> 4;
        lds_w1f[e] = (__bf16)W1[(l4 * 8 + j) * 128 + t * 16 + l15];
        int ks = t >> 1, nn = t & 1;
        lds_w2f[e] = (__bf16)W2[(j * 16 + ks * 4 + l4) * 32 + nn * 16 + l15];
    }
    // ---------- phase 0b: reduced g=1 transform matrices (exact algebra) ----
    if (tid < 192) {
#pragma unroll
        for (int q = 0; q < 3; ++q) {
            int e = tid * 3 + q;            // 0..575
            int c = e & 15;
            int r16 = e >> 4;               // (side*3+j)*6+k
            int k = r16 % 6, sj = r16 / 6, j = sj % 3, side = sj / 3;
            const float* Wm = side ? Wr : Wl;
            int m = k >> 1, isY = k & 1;
            float v = Wm[(4 + 2 * m + isY) * 16 + c];
            if (m == o0[j]) v += Wm[(10 + isY) * 16 + c];
            if (m == o1[j]) v += Wm[(12 + isY) * 16 + c];
            if (m == j)
                v += Wm[(0 + isY) * 16 + c] - Wm[(4 + isY) * 16 + c]
                   - Wm[(6 + isY) * 16 + c] - Wm[(8 + isY) * 16 + c]
                   - Wm[(10 + isY) * 16 + c] - Wm[(12 + isY) * 16 + c];
            lds_wred[side][j][k][c] = v;
        }
    }
    __syncthreads();    // B0: wred + fragments ready

    // ---------- phase 1: GAT ----------
    float px[3], py[3];
    f32x2 xl[3][4], xr[3][4];

    if (g == 0) {
        const float2* ap = reinterpret_cast<const float2*>(agent_pos + b * 6);
#pragma unroll
        for (int j = 0; j < 3; ++j) { px[j] = ap[j].x; py[j] = ap[j].y; }
        // build ALL node features first, then k-outer so each Wl/Wr load serves 3 nodes
        float xf[3][14];
#pragma unroll
        for (int j = 0; j < 3; ++j) {
            const float2 vel = reinterpret_cast<const float2*>(agent_vel + b * 6)[j];
            const float2* rl = reinterpret_cast<const float2*>(rel_lm + b * 18 + j * 6);
            const float4 op  = reinterpret_cast<const float4*>(other_pos + b * 12)[j];
            xf[j][0] = px[j]; xf[j][1] = py[j];
            xf[j][2] = vel.x; xf[j][3] = vel.y;
            xf[j][4] = rl[0].x; xf[j][5] = rl[0].y;
            xf[j][6] = rl[1].x; xf[j][7] = rl[1].y;
            xf[j][8] = rl[2].x; xf[j][9] = rl[2].y;
            xf[j][10] = op.x; xf[j][11] = op.y; xf[j][12] = op.z; xf[j][13] = op.w;
        }
#pragma unroll
        for (int cc = 0; cc < 4; ++cc) {
            f32x2 vbl = ld2(bl + CB + cc * 2), vbr = ld2(br + CB + cc * 2);
#pragma unroll
            for (int j = 0; j < 3; ++j) { xl[j][cc] = vbl; xr[j][cc] = vbr; }
        }
#pragma unroll
        for (int k = 0; k < 14; ++k) {
            f32x2 wl2[4], wr2[4];
#pragma unroll
            for (int cc = 0; cc < 4; ++cc) {
                wl2[cc] = ld2(Wl + k * 16 + CB + cc * 2);
                wr2[cc] = ld2(Wr + k * 16 + CB + cc * 2);
            }
#pragma unroll
            for (int j = 0; j < 3; ++j) {
                f32x2 xk = splat2(xf[j][k]);
#pragma unroll
                for (int cc = 0; cc < 4; ++cc) {
                    xl[j][cc] = pk_fma(xk, wl2[cc], xl[j][cc]);
                    xr[j][cc] = pk_fma(xk, wr2[cc], xr[j][cc]);
                }
            }
        }
    } else {
        const float2* lp2 = reinterpret_cast<const float2*>(lm_pos + b * 18);
#pragma unroll
        for (int m = 0; m < 3; ++m) { px[m] = lp2[m].x; py[m] = lp2[m].y; }
        float ps[6] = {px[0], py[0], px[1], py[1], px[2], py[2]};
#pragma unroll
        for (int cc = 0; cc < 4; ++cc) {
            f32x2 vbl = ld2(bl + CB + cc * 2), vbr = ld2(br + CB + cc * 2);
#pragma unroll
            for (int j = 0; j < 3; ++j) { xl[j][cc] = vbl; xr[j][cc] = vbr; }
        }
#pragma unroll
        for (int k = 0; k < 6; ++k) {
            f32x2 pk = splat2(ps[k]);
#pragma unroll
            for (int j = 0; j < 3; ++j) {
#pragma unroll
                for (int cc = 0; cc < 4; ++cc) {
                    xl[j][cc] = pk_fma(pk, ld2(&lds_wred[0][j][k][CB + cc * 2]), xl[j][cc]);
                    xr[j][cc] = pk_fma(pk, ld2(&lds_wred[1][j][k][CB + cc * 2]), xr[j][cc]);
                }
            }
        }
    }

    // ---- pairwise distances + edge geometry (precomputed once, e = j*3+i) ----
    float ax[9], ay[9], ad[9];
    {
        float dx, dy, d01, d02, d12;
        dx = px[0] - px[1]; dy = py[0] - py[1]; d01 = sqrtf(dx * dx + dy * dy);
        dx = px[0] - px[2]; dy = py[0] - py[2]; d02 = sqrtf(dx * dx + dy * dy);
        dx = px[1] - px[2]; dy = py[1] - py[2]; d12 = sqrtf(dx * dx + dy * dy);
#pragma unroll
        for (int i = 0; i < 3; ++i) {
#pragma unroll
            for (int j = 0; j < 3; ++j) {
                int e = j * 3 + i;
                if (i == j) {
                    const int a = o0[i], c2 = o1[i];
                    ax[e] = 0.5f * (px[a] + px[c2]) - px[i];
                    ay[e] = 0.5f * (py[a] + py[c2]) - py[i];
                    const float dA = (i == 0) ? d01 : ((i == 1) ? d01 : d02);
                    const float dB = (i == 0) ? d02 : ((i == 1) ? d12 : d12);
                    ad[e] = 0.5f * (dA + dB);
                } else {
                    ax[e] = px[j] - px[i];
                    ay[e] = py[j] - py[i];
                    ad[e] = ((i == 0 && j == 1) || (i == 1 && j == 0)) ? d01
                          : ((i == 0 && j == 2) || (i == 2 && j == 0)) ? d02 : d12;
                }
            }
        }
    }

    // ---- logit partials: cc-outer so each We/att load serves all 9 edges ----
    f32x2 lpacc[9];
#pragma unroll
    for (int e = 0; e < 9; ++e) lpacc[e] = splat2(0.f);
#pragma unroll
    for (int cc = 0; cc < 4; ++cc) {
        f32x2 we0 = ld2(We + CB + cc * 2);
        f32x2 we1 = ld2(We + 16 + CB + cc * 2);
        f32x2 we2 = ld2(We + 32 + CB + cc * 2);
        f32x2 vat = ld2(att + CB + cc * 2);
#pragma unroll
        for (int j = 0; j < 3; ++j) {
#pragma unroll
            for (int i = 0; i < 3; ++i) {
                int e = j * 3 + i;
                f32x2 gg = xl[j][cc] + xr[i][cc];
                gg = pk_fma(splat2(ax[e]), we0, gg);
                gg = pk_fma(splat2(ay[e]), we1, gg);
                gg = pk_fma(splat2(ad[e]), we2, gg);
                f32x2 lk = pk_max(gg, gg * splat2(NEG_SLOPE));
                lpacc[e] = pk_fma(lk, vat, lpacc[e]);
            }
        }
    }
    float lp[9];
#pragma unroll
    for (int e = 0; e < 9; ++e) lp[e] = lpacc[e].x + lpacc[e].y;

    // ---- exchange partials with sibling channel-half ----
#define LPX(gg, cc2, ss, ee) lds_lp[(((gg) * 2 + (cc2)) * 64 + (ss)) * 9 + (ee)]
#pragma unroll
    for (int e = 0; e < 9; ++e) LPX(g, ch, lane, e) = lp[e];
    __syncthreads();    // B1

    float lg[9];
#pragma unroll
    for (int e = 0; e < 9; ++e) lg[e] = lp[e] + LPX(g, 1 - ch, lane, e);

    // ---- softmax per target (logits O(10), no max-sub) + pooled relu-sum ----
    f32x2 vb[4];
#pragma unroll
    for (int cc = 0; cc < 4; ++cc) vb[cc] = ld2(bias + CB + cc * 2);
    f32x2 hs[4] = {{0,0},{0,0},{0,0},{0,0}};
    const f32x2 zero2 = {0.f, 0.f};
#pragma unroll
    for (int i = 0; i < 3; ++i) {
        float e0 = __expf(lg[i]);
        float e1 = __expf(lg[3 + i]);
        float e2 = __expf(lg[6 + i]);
        float inv = __builtin_amdgcn_rcpf(e0 + e1 + e2);
        f32x2 a0 = splat2(e0 * inv), a1 = splat2(e1 * inv), a2 = splat2(e2 * inv);
#pragma unroll
        for (int cc = 0; cc < 4; ++cc) {
            f32x2 v = pk_fma(a0, xl[0][cc],
                      pk_fma(a1, xl[1][cc],
                      pk_fma(a2, xl[2][cc], vb[cc])));
            hs[cc] += pk_max(v, zero2);
        }
    }

    // ---- publish pooled h as bf16 into LDS ----
    {
        bf16x8 hv;
#pragma unroll
        for (int cc = 0; cc < 4; ++cc) {
            hv[cc * 2 + 0] = (__bf16)hs[cc].x;
            hv[cc * 2 + 1] = (__bf16)hs[cc].y;
        }
        *reinterpret_cast<bf16x8*>(&lds_h[lane][g * 16 + CB]) = hv;
    }
    __syncthreads();    // B2: h ready

    // ---------- phase 2: MLP via MFMA 16x16x32 bf16 (R8 layout, validated) ----------
    const int l15 = lane & 15;
    const int l4  = lane >> 4;
    const f32x4 zero4 = {0.f, 0.f, 0.f, 0.f};

    float b1v[8], b2v[2];
#pragma unroll
    for (int n = 0; n < 8; ++n) b1v[n] = b1[n * 16 + l15];
#pragma unroll
    for (int nn = 0; nn < 2; ++nn) b2v[nn] = b2[nn * 16 + l15];

    // layer 1: z[16x128] = h[16x32] @ W1 + b1, relu
    bf16x8 a1 = *reinterpret_cast<const bf16x8*>(&lds_h[wu * 16 + l15][l4 * 8]);
    f32x4 acc[8];
#pragma unroll
    for (int n = 0; n < 8; ++n) {
        bf16x8 bfrag = *reinterpret_cast<const bf16x8*>(&lds_w1f[((n << 6) | lane) * 8]);
        acc[n] = __builtin_amdgcn_mfma_f32_16x16x32_bf16(a1, bfrag, zero4, 0, 0, 0);
    }
#pragma unroll
    for (int r = 0; r < 4; ++r) {
        bf16x8 zv;
#pragma unroll
        for (int n = 0; n < 8; ++n) zv[n] = (__bf16)relu_f(acc[n][r] + b1v[n]);
        *reinterpret_cast<bf16x8*>(&lds_z[wu][l4 * 4 + r][l15 * 8]) = zv;
    }

    // layer 2: o[16x32] = z @ W2 + b2 (same-wave z reuse, compiler waits lgkmcnt)
    f32x4 o2[2] = {zero4, zero4};
#pragma unroll
    for (int ks = 0; ks < 4; ++ks) {
        bf16x8 a2 = *reinterpret_cast<const bf16x8*>(&lds_z[wu][l15][ks * 32 + l4 * 8]);
#pragma unroll
        for (int nn = 0; nn < 2; ++nn) {
            bf16x8 bfrag = *reinterpret_cast<const bf16x8*>(&lds_w2f[(((ks * 2 + nn) << 6) | lane) * 8]);
            o2[nn] = __builtin_amdgcn_mfma_f32_16x16x32_bf16(a2, bfrag, o2[nn], 0, 0, 0);
        }
    }

    // store: lane holds o[l4*4+r][nn*16+l15]
#pragma unroll
    for (int nn = 0; nn < 2; ++nn) {
#pragma unroll
        for (int r = 0; r < 4; ++r) {
            int row = blockIdx.x * 64 + wu * 16 + l4 * 4 + r;
            if (row < Btot)
                out[(size_t)row * 32 + nn * 16 + l15] = o2[nn][r] + b2v[nn];
        }
    }
}

extern "C" void kernel_launch(void* const* d_in, const int* in_sizes, int n_in,
                              void* d_out, int out_size, void* d_ws, size_t ws_size,
                              hipStream_t stream) {
    const float* agent_pos = (const float*)d_in[0];
    const float* agent_vel = (const float*)d_in[1];
    const float* rel_lm    = (const float*)d_in[2];
    const float* other_pos = (const float*)d_in[3];
    const float* lm_pos    = (const float*)d_in[4];
    const float* Wl   = (const float*)d_in[5];
    const float* bl   = (const float*)d_in[6];
    const float* Wr   = (const float*)d_in[7];
    const float* br   = (const float*)d_in[8];
    const float* We   = (const float*)d_in[9];
    const float* att  = (const float*)d_in[10];
    const float* bias = (const float*)d_in[11];
    const float* W1   = (const float*)d_in[12];
    const float* b1   = (const float*)d_in[13];
    const float* W2   = (const float*)d_in[14];
    const float* b2   = (const float*)d_in[15];
    float* out = (float*)d_out;

    int B = in_sizes[0] / 6;                  // agent_pos is [B,3,2]
    int grid = (B + 63) / 64;
    scl_fused_kernel<<<grid, 256, 0, stream>>>(
        agent_pos, agent_vel, rel_lm, other_pos, lm_pos,
        Wl, bl, Wr, br, We, att, bias, W1, b1, W2, b2, out, B);
}